// Round 1
// baseline (1410.991 us; speedup 1.0000x reference)
//
#include <hip/hip_runtime.h>
#include <hip/hip_bf16.h>

#define NN 500000
#define EE 2000000
#define GG 16384
#define ND 44
#define ED 12
#define HH 64
#define EMB 128

typedef __attribute__((ext_vector_type(8))) short bf16x8;
typedef __attribute__((ext_vector_type(4))) float f32x4;

// fp32 -> bf16 round-to-nearest-even, bit pattern as short
__device__ inline short f2bf(float v) {
    unsigned int x = __builtin_bit_cast(unsigned int, v);
    x += 0x7FFFu + ((x >> 16) & 1u);
    return (short)(x >> 16);
}

// ---------------------------------------------------------------------------
// Weight prep: transpose to [n][k] layout, cast to bf16, zero-pad K of w1a to 64
// Output layout in `o` (shorts): w1a_t[64][64] | w1b_t[64][64] | w2a_t[128][64] | w2b_t[128][128]
__global__ __launch_bounds__(256) void prep_weights(
    const float* __restrict__ w1a, const float* __restrict__ w1b,
    const float* __restrict__ w2a, const float* __restrict__ w2b,
    short* __restrict__ o) {
    int t = blockIdx.x * 256 + threadIdx.x;
    if (t < 4096) {
        int n = t >> 6, k = t & 63;
        o[t] = f2bf(k < ND ? w1a[k * HH + n] : 0.f);
    } else if (t < 8192) {
        int u = t - 4096; int n = u >> 6, k = u & 63;
        o[t] = f2bf(w1b[k * HH + n]);
    } else if (t < 16384) {
        int u = t - 8192; int n = u >> 6, k = u & 63;
        o[t] = f2bf(w2a[k * EMB + n]);
    } else if (t < 32768) {
        int u = t - 16384; int n = u >> 7, k = u & 127;
        o[t] = f2bf(w2b[k * EMB + n]);
    }
}

// ---------------------------------------------------------------------------
// Edge layer 1: msg = relu(x[src] + ea @ el1_w + el1_b), scatter-add to agg1[dst] (44 dims)
__global__ __launch_bounds__(256) void edge1(
    const float* __restrict__ x, const float* __restrict__ ea,
    const int* __restrict__ ei, const float* __restrict__ ew,
    const float* __restrict__ eb, float* __restrict__ agg1) {
    __shared__ float W[ED * 64];   // cols padded to 64, zeros beyond ND
    __shared__ float B[64];
    for (int i = threadIdx.x; i < ED * 64; i += 256) {
        int k = i >> 6, c = i & 63;
        W[i] = (c < ND) ? ew[k * ND + c] : 0.f;
    }
    if (threadIdx.x < 64) B[threadIdx.x] = (threadIdx.x < ND) ? eb[threadIdx.x] : 0.f;
    __syncthreads();
    int lane = threadIdx.x & 63;
    int w = (blockIdx.x << 2) + (threadIdx.x >> 6);
    int nw = gridDim.x << 2;
    for (int e = w; e < EE; e += nw) {
        int src = ei[e], dst = ei[EE + e];
        float eav = (lane < ED) ? ea[e * ED + lane] : 0.f;
        float acc = B[lane];
#pragma unroll
        for (int k = 0; k < ED; ++k)
            acc += __shfl(eav, k) * W[k * 64 + lane];
        if (lane < ND) {
            float m = x[src * ND + lane] + acc;
            if (m > 0.f) atomicAdd(&agg1[dst * ND + lane], m);  // relu==0 -> skip
        }
    }
}

// Edge layer 2: msg = relu(h[src] + ea @ el2_w + el2_b), scatter-add to agg2[dst] (64 dims)
__global__ __launch_bounds__(256) void edge2(
    const float* __restrict__ h, const float* __restrict__ ea,
    const int* __restrict__ ei, const float* __restrict__ ew,
    const float* __restrict__ eb, float* __restrict__ agg2) {
    __shared__ float W[ED * HH];
    __shared__ float B[HH];
    for (int i = threadIdx.x; i < ED * HH; i += 256) W[i] = ew[i];
    if (threadIdx.x < HH) B[threadIdx.x] = eb[threadIdx.x];
    __syncthreads();
    int lane = threadIdx.x & 63;
    int w = (blockIdx.x << 2) + (threadIdx.x >> 6);
    int nw = gridDim.x << 2;
    for (int e = w; e < EE; e += nw) {
        int src = ei[e], dst = ei[EE + e];
        float eav = (lane < ED) ? ea[e * ED + lane] : 0.f;
        float acc = B[lane];
#pragma unroll
        for (int k = 0; k < ED; ++k)
            acc += __shfl(eav, k) * W[k * HH + lane];
        float m = h[src * HH + lane] + acc;
        if (m > 0.f) atomicAdd(&agg2[dst * HH + lane], m);
    }
}

// ---------------------------------------------------------------------------
// Node MLP 1: h = relu( relu((x+agg1) @ w1a + b1a) @ w1b + b1b ), 44(->64 pad)->64->64
// One wave per 16 nodes; mfma_f32_16x16x32_bf16.
#define HSTR1 68  // f32 LDS row stride (pad 64+4 to break bank alignment)
__global__ __launch_bounds__(256) void mlp1(
    const float* __restrict__ x, const float* __restrict__ agg1,
    const short* __restrict__ w1a_t, const float* __restrict__ b1a,
    const short* __restrict__ w1b_t, const float* __restrict__ b1b,
    float* __restrict__ h) {
    __shared__ float hid[4][16 * HSTR1];
    int lane = threadIdx.x & 63;
    int wv = threadIdx.x >> 6;
    int tile = blockIdx.x * 4 + wv;
    bool act = tile < (NN / 16);
    int tile_c = act ? tile : (NN / 16 - 1);
    int node0 = tile_c * 16;
    int mrow = lane & 15, q = lane >> 4;
    int m = node0 + mrow;
    float* hw = hid[wv];

    // A frags: in = x + agg1, K padded 44->64 with zeros
    bf16x8 afrag[2];
#pragma unroll
    for (int s = 0; s < 2; ++s) {
#pragma unroll
        for (int j = 0; j < 8; ++j) {
            int k = s * 32 + q * 8 + j;
            float v = (k < ND) ? (x[m * ND + k] + agg1[m * ND + k]) : 0.f;
            afrag[s][j] = f2bf(v);
        }
    }
    // stage 1: hidden = relu(in @ w1a + b1a) -> LDS (f32)
#pragma unroll
    for (int nt = 0; nt < 4; ++nt) {
        int n = nt * 16 + mrow;
        float bias = b1a[n];
        f32x4 acc = {bias, bias, bias, bias};
#pragma unroll
        for (int s = 0; s < 2; ++s) {
            bf16x8 bfrag = *(const bf16x8*)(w1a_t + n * 64 + s * 32 + q * 8);
            acc = __builtin_amdgcn_mfma_f32_16x16x32_bf16(afrag[s], bfrag, acc, 0, 0, 0);
        }
#pragma unroll
        for (int r = 0; r < 4; ++r)
            hw[(q * 4 + r) * HSTR1 + n] = fmaxf(acc[r], 0.f);
    }
    __syncthreads();
    // stage 2 A frags from LDS
    bf16x8 af2[2];
#pragma unroll
    for (int s = 0; s < 2; ++s) {
        f32x4 v0 = *(const f32x4*)(hw + mrow * HSTR1 + s * 32 + q * 8);
        f32x4 v1 = *(const f32x4*)(hw + mrow * HSTR1 + s * 32 + q * 8 + 4);
#pragma unroll
        for (int j = 0; j < 4; ++j) { af2[s][j] = f2bf(v0[j]); af2[s][j + 4] = f2bf(v1[j]); }
    }
#pragma unroll
    for (int nt = 0; nt < 4; ++nt) {
        int n = nt * 16 + mrow;
        float bias = b1b[n];
        f32x4 acc = {bias, bias, bias, bias};
#pragma unroll
        for (int s = 0; s < 2; ++s) {
            bf16x8 bfrag = *(const bf16x8*)(w1b_t + n * 64 + s * 32 + q * 8);
            acc = __builtin_amdgcn_mfma_f32_16x16x32_bf16(af2[s], bfrag, acc, 0, 0, 0);
        }
        if (act) {
#pragma unroll
            for (int r = 0; r < 4; ++r)
                h[(node0 + q * 4 + r) * HH + n] = fmaxf(acc[r], 0.f);
        }
    }
}

// ---------------------------------------------------------------------------
// Node MLP 2 + fused mean-pool accumulate: out = relu((h+agg2)@w2a+b2a) @ w2b + b2b
// then segmented (batch-sorted) column sums -> atomicAdd into sums[G][128].
#define HSTR2 132  // f32 LDS row stride for 128 cols
__global__ __launch_bounds__(256) void mlp2(
    const float* __restrict__ h, const float* __restrict__ agg2,
    const short* __restrict__ w2a_t, const float* __restrict__ b2a,
    const short* __restrict__ w2b_t, const float* __restrict__ b2b,
    const int* __restrict__ batch, float* __restrict__ sums) {
    __shared__ float buf[4][16 * HSTR2];
    int lane = threadIdx.x & 63;
    int wv = threadIdx.x >> 6;
    int tile = blockIdx.x * 4 + wv;
    bool act = tile < (NN / 16);
    int tile_c = act ? tile : (NN / 16 - 1);
    int node0 = tile_c * 16;
    int mrow = lane & 15, q = lane >> 4;
    int m = node0 + mrow;
    float* bw = buf[wv];

    // A frags: in2 = h + agg2 (K=64), vectorized f32x4 loads
    bf16x8 afrag[2];
#pragma unroll
    for (int s = 0; s < 2; ++s) {
        f32x4 h0 = *(const f32x4*)(h + m * HH + s * 32 + q * 8);
        f32x4 h1 = *(const f32x4*)(h + m * HH + s * 32 + q * 8 + 4);
        f32x4 a0 = *(const f32x4*)(agg2 + m * HH + s * 32 + q * 8);
        f32x4 a1 = *(const f32x4*)(agg2 + m * HH + s * 32 + q * 8 + 4);
#pragma unroll
        for (int j = 0; j < 4; ++j) {
            afrag[s][j] = f2bf(h0[j] + a0[j]);
            afrag[s][j + 4] = f2bf(h1[j] + a1[j]);
        }
    }
    // stage 1: hidden[16][128] = relu(in2 @ w2a + b2a) -> LDS f32
#pragma unroll
    for (int nt = 0; nt < 8; ++nt) {
        int n = nt * 16 + mrow;
        float bias = b2a[n];
        f32x4 acc = {bias, bias, bias, bias};
#pragma unroll
        for (int s = 0; s < 2; ++s) {
            bf16x8 bfrag = *(const bf16x8*)(w2a_t + n * HH + s * 32 + q * 8);
            acc = __builtin_amdgcn_mfma_f32_16x16x32_bf16(afrag[s], bfrag, acc, 0, 0, 0);
        }
#pragma unroll
        for (int r = 0; r < 4; ++r)
            bw[(q * 4 + r) * HSTR2 + n] = fmaxf(acc[r], 0.f);
    }
    __syncthreads();
    // stage 2 A frags (K=128) from LDS
    bf16x8 af2[4];
#pragma unroll
    for (int s = 0; s < 4; ++s) {
        f32x4 v0 = *(const f32x4*)(bw + mrow * HSTR2 + s * 32 + q * 8);
        f32x4 v1 = *(const f32x4*)(bw + mrow * HSTR2 + s * 32 + q * 8 + 4);
#pragma unroll
        for (int j = 0; j < 4; ++j) { af2[s][j] = f2bf(v0[j]); af2[s][j + 4] = f2bf(v1[j]); }
    }
    __syncthreads();
    // stage 2: out[16][128] = hidden @ w2b + b2b
    f32x4 oacc[8];
#pragma unroll
    for (int nt = 0; nt < 8; ++nt) {
        int n = nt * 16 + mrow;
        float bias = b2b[n];
        f32x4 acc = {bias, bias, bias, bias};
#pragma unroll
        for (int s = 0; s < 4; ++s) {
            bf16x8 bfrag = *(const bf16x8*)(w2b_t + n * EMB + s * 32 + q * 8);
            acc = __builtin_amdgcn_mfma_f32_16x16x32_bf16(af2[s], bfrag, acc, 0, 0, 0);
        }
        oacc[nt] = acc;
    }
    // reuse bw as the out tile for pooling
#pragma unroll
    for (int nt = 0; nt < 8; ++nt)
#pragma unroll
        for (int r = 0; r < 4; ++r)
            bw[(q * 4 + r) * HSTR2 + nt * 16 + mrow] = oacc[nt][r];
    __syncthreads();
    // segmented pool: batch is sorted; run-flush per column. lane handles cols lane, lane+64
    int bv = (act && lane < 16) ? batch[node0 + lane] : 0;
    if (act) {
#pragma unroll
        for (int cp = 0; cp < 2; ++cp) {
            int col = lane + cp * 64;
            float run = 0.f;
            int bprev = __shfl(bv, 0);
            for (int i = 0; i < 16; ++i) {
                int bg = __shfl(bv, i);
                if (bg != bprev) {
                    atomicAdd(&sums[bprev * EMB + col], run);
                    run = 0.f; bprev = bg;
                }
                run += bw[i * HSTR2 + col];
            }
            atomicAdd(&sums[bprev * EMB + col], run);
        }
    }
}

// ---------------------------------------------------------------------------
// Finalize: per-graph node count via binary search on sorted batch; out = sums / max(cnt,1)
__global__ __launch_bounds__(128) void finalize(
    const float* __restrict__ sums, const int* __restrict__ batch,
    float* __restrict__ out) {
    int g = blockIdx.x;
    __shared__ int cnt_s;
    if (threadIdx.x == 0) {
        int lo = 0, hi = NN;
        while (lo < hi) { int mid = (lo + hi) >> 1; if (batch[mid] < g) lo = mid + 1; else hi = mid; }
        int lo2 = lo, hi2 = NN;
        while (lo2 < hi2) { int mid = (lo2 + hi2) >> 1; if (batch[mid] < g + 1) lo2 = mid + 1; else hi2 = mid; }
        cnt_s = lo2 - lo;
    }
    __syncthreads();
    int c = cnt_s > 1 ? cnt_s : 1;
    out[g * EMB + threadIdx.x] = sums[g * EMB + threadIdx.x] / (float)c;
}

// ---------------------------------------------------------------------------
extern "C" void kernel_launch(void* const* d_in, const int* in_sizes, int n_in,
                              void* d_out, int out_size, void* d_ws, size_t ws_size,
                              hipStream_t stream) {
    const float* x    = (const float*)d_in[0];
    const float* ea   = (const float*)d_in[1];
    const int*   ei   = (const int*)d_in[2];
    const int*   batch= (const int*)d_in[3];
    const float* el1w = (const float*)d_in[4];
    const float* el1b = (const float*)d_in[5];
    const float* w1a  = (const float*)d_in[6];
    const float* b1a  = (const float*)d_in[7];
    const float* w1b  = (const float*)d_in[8];
    const float* b1b  = (const float*)d_in[9];
    const float* el2w = (const float*)d_in[10];
    const float* el2b = (const float*)d_in[11];
    const float* w2a  = (const float*)d_in[12];
    const float* b2a  = (const float*)d_in[13];
    const float* w2b  = (const float*)d_in[14];
    const float* b2b  = (const float*)d_in[15];

    char* ws = (char*)d_ws;
    float* agg1 = (float*)ws;                                   // N*44*4 = 88,000,000 B
    float* hbuf = (float*)(ws + 88000000);                      // N*64*4 = 128,000,000 B
    float* agg2 = (float*)(ws + 216000000);                     // N*64*4 = 128,000,000 B
    float* sums = (float*)(ws + 344000000);                     // G*128*4 = 8,388,608 B
    short* wts  = (short*)(ws + 352388608);                     // 32768*2 B
    short* w1a_t = wts;
    short* w1b_t = wts + 4096;
    short* w2a_t = wts + 8192;
    short* w2b_t = wts + 16384;

    hipMemsetAsync(agg1, 0, (size_t)NN * ND * 4, stream);
    hipMemsetAsync(agg2, 0, (size_t)NN * HH * 4, stream);
    hipMemsetAsync(sums, 0, (size_t)GG * EMB * 4, stream);

    prep_weights<<<128, 256, 0, stream>>>(w1a, w1b, w2a, w2b, wts);
    edge1<<<4096, 256, 0, stream>>>(x, ea, ei, el1w, el1b, agg1);
    mlp1<<<7813, 256, 0, stream>>>(x, agg1, w1a_t, b1a, w1b_t, b1b, hbuf);
    edge2<<<4096, 256, 0, stream>>>(hbuf, ea, ei, el2w, el2b, agg2);
    mlp2<<<7813, 256, 0, stream>>>(hbuf, agg2, w2a_t, b2a, w2b_t, b2b, batch, sums);
    finalize<<<GG, 128, 0, stream>>>(sums, batch, (float*)d_out);
}